// Round 1
// baseline (569.092 us; speedup 1.0000x reference)
//
#include <hip/hip_runtime.h>
#include <hip/hip_bf16.h>
#include <math.h>

#define N_NODES 8192
#define IN_F    512
#define OUT_F   128
#define LRELU_A 0.2f
#define EPS_BN  1e-5f
#define MSH     40.0f                // static softmax shift (upper bound on lrelu(max s1+max s2))
#define NSPLIT  8
#define JSPAN   (N_NODES / NSPLIT)   // 1024
#define TILE_I  64                   // 4 waves x 16 rows
#define ASTR    36                   // k_h A-tile row stride (32 + 4 pad) in floats
#define MSTR    34                   // LDS mask row stride in u32 (32 + 2 pad, even for u64 align)

typedef unsigned short u16;
typedef unsigned int   u32;
typedef unsigned long long u64;
typedef __attribute__((ext_vector_type(8))) short  short8;
typedef __attribute__((ext_vector_type(4))) float  floatx4;

__device__ __forceinline__ u16 f2bf_rtn(float x) {
    u32 u = __float_as_uint(x);
    return (u16)((u + 0x7fffu + ((u >> 16) & 1u)) >> 16);
}

// ---------------- hamT bf16 [128 c][512 k]; zero s1/s2/cs/cq ----------------
__global__ __launch_bounds__(256) void k_hamT(const float* __restrict__ W, u16* __restrict__ hamT,
                                              float* __restrict__ s1, float* __restrict__ s2,
                                              float* __restrict__ cs, float* __restrict__ cq) {
    const int idx = blockIdx.x * 256 + threadIdx.x;   // 65536
    if (idx < N_NODES) { s1[idx] = 0.f; s2[idx] = 0.f; }
    if (idx < OUT_F)   { cs[idx] = 0.f; cq[idx] = 0.f; }
    const int c = idx >> 9, k = idx & 511;
    const int b = c >> 5, cc = c & 31, p = k >> 7, q = k & 127;
    const u32 NEGMASK = 0x284Eu;     // bit (b*4+p) set => sign -1
    const float sg = ((NEGMASK >> (b * 4 + p)) & 1u) ? -1.f : 1.f;
    hamT[idx] = f2bf_rtn(sg * W[q * 128 + (b ^ p) * 32 + cc]);
}

// ---------------- h = input @ ham via MFMA; LDS-staged A (coalesced); emit hT + s1/s2 ----------------
// grid (128, 2) x 256 thr. Block: 64 i x 64 c (c-half); wave = 16 i x 64 c. K=512 in 16 steps.
__global__ __launch_bounds__(256) void k_h(const float* __restrict__ inp, const u16* __restrict__ hamT,
                                           const float* __restrict__ a,
                                           u16* __restrict__ hT, float* __restrict__ s1, float* __restrict__ s2) {
    __shared__ float inA[2][64 * ASTR];    // 2 x 9216 B
    const int t = threadIdx.x;
    const int lane = t & 63, wid = t >> 6;
    const int quad = lane >> 4, n = lane & 15;
    const int i0 = blockIdx.x * 64;
    const int chalf = blockIdx.y;
    const int srow = t >> 2, scol = (t & 3) * 8;     // staging map: 64 B per thread per step

    // stage step 0
    {
        const float* sp = inp + (size_t)(i0 + srow) * IN_F + scol;
        *(float4*)&inA[0][srow * ASTR + scol]     = *(const float4*)sp;
        *(float4*)&inA[0][srow * ASTR + scol + 4] = *(const float4*)(sp + 4);
    }
    __syncthreads();

    floatx4 acc[4];
#pragma unroll
    for (int ct = 0; ct < 4; ct++) acc[ct] = (floatx4){0.f, 0.f, 0.f, 0.f};

#pragma unroll 2
    for (int kk = 0; kk < 16; ++kk) {
        const int cur = kk & 1;
        float4 f0n, f1n;
        const bool more = (kk + 1 < 16);
        if (more) {
            const float* sp = inp + (size_t)(i0 + srow) * IN_F + (kk + 1) * 32 + scol;
            f0n = *(const float4*)sp;
            f1n = *(const float4*)(sp + 4);
        }
        float4 a0 = *(const float4*)&inA[cur][(wid * 16 + n) * ASTR + quad * 8];
        float4 a1 = *(const float4*)&inA[cur][(wid * 16 + n) * ASTR + quad * 8 + 4];
        union { u32 u[4]; short8 s; } fa;
        fa.u[0] = (u32)f2bf_rtn(a0.x) | ((u32)f2bf_rtn(a0.y) << 16);
        fa.u[1] = (u32)f2bf_rtn(a0.z) | ((u32)f2bf_rtn(a0.w) << 16);
        fa.u[2] = (u32)f2bf_rtn(a1.x) | ((u32)f2bf_rtn(a1.y) << 16);
        fa.u[3] = (u32)f2bf_rtn(a1.z) | ((u32)f2bf_rtn(a1.w) << 16);
#pragma unroll
        for (int ct = 0; ct < 4; ++ct) {
            short8 fb = *(const short8*)&hamT[(chalf * 64 + ct * 16 + n) * IN_F + kk * 32 + quad * 8];
            acc[ct] = __builtin_amdgcn_mfma_f32_16x16x32_bf16(fa.s, fb, acc[ct], 0, 0, 0);
        }
        if (more) {
            *(float4*)&inA[cur ^ 1][srow * ASTR + scol]     = f0n;
            *(float4*)&inA[cur ^ 1][srow * ASTR + scol + 4] = f1n;
        }
        __syncthreads();
    }

    // hT store (C layout: row=quad*4+r, col=chalf*64+ct*16+n); pack 4 rows -> u64
    const int iw = i0 + wid * 16;
#pragma unroll
    for (int ct = 0; ct < 4; ++ct) {
        const int c = chalf * 64 + ct * 16 + n;
        u64 pk = (u64)f2bf_rtn(acc[ct][0])
               | ((u64)f2bf_rtn(acc[ct][1]) << 16)
               | ((u64)f2bf_rtn(acc[ct][2]) << 32)
               | ((u64)f2bf_rtn(acc[ct][3]) << 48);
        *(u64*)&hT[(size_t)c * N_NODES + iw + quad * 4] = pk;
    }

    // s1/s2 partials (this c-half) -> global atomics
    float p1[4] = {0.f, 0.f, 0.f, 0.f}, p2[4] = {0.f, 0.f, 0.f, 0.f};
#pragma unroll
    for (int ct = 0; ct < 4; ++ct) {
        const int c = chalf * 64 + ct * 16 + n;
        const float a1v = a[c], a2v = a[OUT_F + c];
#pragma unroll
        for (int r = 0; r < 4; ++r) { p1[r] += acc[ct][r] * a1v; p2[r] += acc[ct][r] * a2v; }
    }
#pragma unroll
    for (int m = 1; m < 16; m <<= 1) {
#pragma unroll
        for (int r = 0; r < 4; ++r) {
            p1[r] += __shfl_xor(p1[r], m, 64);
            p2[r] += __shfl_xor(p2[r], m, 64);
        }
    }
    if (n == 0) {
#pragma unroll
        for (int r = 0; r < 4; ++r) {
            atomicAdd(&s1[iw + quad * 4 + r], p1[r]);
            atomicAdd(&s2[iw + quad * 4 + r], p2[r]);
        }
    }
}

// ---------------- fused MFMA attention: barrier-free main loop, B-frags direct from L2-resident hT ----------------
// grid (128, NSPLIT) x 256 thr. Block: 64 i x 128 c over JSPAN=1024 j; 16 chunks of 64 j.
// Phase A: each wave ballot-packs its 16 adj rows into LDS masks (1 KB/instr coalesced) — wave-local data.
// Phase B: per chunk {issue 16 global B-frag loads (vmcnt) -> softmax VALU from LDS (lgkmcnt) -> 16 MFMA}.
// hT is 2 MB total => L2-resident; no LDS staging, no per-chunk __syncthreads (waves free-run).
__global__ __launch_bounds__(256, 3) void k_att(const int* __restrict__ adj, const u16* __restrict__ hT,
                                                const float* __restrict__ s1, const float* __restrict__ s2,
                                                float* __restrict__ Opart, float* __restrict__ Lpart) {
    __shared__ float s2s[JSPAN];           // 4 KB (keeps A-frag reads on lgkmcnt, not vmcnt)
    __shared__ u32 mk[64 * MSTR];          // 8704 B
    const int t = threadIdx.x;
    const int lane = t & 63, wid = t >> 6;
    const int quad = lane >> 4, n = lane & 15;
    const int i0 = blockIdx.x * TILE_I;
    const int jbase = blockIdx.y * JSPAN;
    const int i_lane = i0 + wid * 16 + n;
    const float s1v = s1[i_lane];

    *(float4*)&s2s[t * 4] = *(const float4*)&s2[jbase + t * 4];

    // ---- Phase A: pack this wave's 16 rows of adj into LDS masks ----
    {
        const size_t rowbase = (size_t)(i0 + wid * 16);
#pragma unroll
        for (int rb = 0; rb < 4; ++rb) {
            uint4 v[4][4];
#pragma unroll
            for (int r = 0; r < 4; ++r) {
                const int* ap = adj + (rowbase + rb * 4 + r) * N_NODES + jbase + lane * 4;
#pragma unroll
                for (int g = 0; g < 4; ++g) v[r][g] = *(const uint4*)(ap + g * 256);
            }
#pragma unroll
            for (int r = 0; r < 4; ++r) {
                u32* mp = &mk[(wid * 16 + rb * 4 + r) * MSTR];
#pragma unroll
                for (int g = 0; g < 4; ++g) {
                    u64 c0 = __ballot((int)v[r][g].x > 0);
                    u64 c1 = __ballot((int)v[r][g].y > 0);
                    u64 c2 = __ballot((int)v[r][g].z > 0);
                    u64 c3 = __ballot((int)v[r][g].w > 0);
                    if (lane < 4) {
                        u64 val = (lane == 0) ? c0 : (lane == 1) ? c1 : (lane == 2) ? c2 : c3;
                        *(u64*)&mp[g * 8 + lane * 2] = val;
                    }
                }
            }
        }
    }
    __syncthreads();   // s2s + mk visible; the ONLY barrier in this kernel

    const u32* mrow = &mk[(wid * 16 + n) * MSTR];
    const u16* hrow = hT + (size_t)n * N_NODES + jbase + quad * 8;

    floatx4 acc[8];
#pragma unroll
    for (int ct = 0; ct < 8; ct++) acc[ct] = (floatx4){0.f, 0.f, 0.f, 0.f};
    float Lacc = 0.f;

#pragma unroll 1
    for (int g = 0; g < 4; ++g) {          // 4 mask groups x 4 chunks = 16 chunks of 64 j
        u32 m8[8];
#pragma unroll
        for (int w = 0; w < 8; ++w) m8[w] = mrow[g * 8 + w];
#pragma unroll
        for (int chi = 0; chi < 4; ++chi) {       // chi compile-time: all m8 indices static
            const int ch = g * 4 + chi;
            // issue all 16 B-frag loads first (hT is L2-resident; 16x64B fully-used segments)
            short8 fb0[8], fb1[8];
#pragma unroll
            for (int ct = 0; ct < 8; ++ct) {
                const u16* hp_ = hrow + (size_t)(ct * 16) * N_NODES + ch * 64;
                fb0[ct] = *(const short8*)hp_;
                fb1[ct] = *(const short8*)(hp_ + 32);
            }
            // A-frag softmax build (~480 VALU cycles) hides the vmcnt latency
            short8 fa[2];
#pragma unroll
            for (int ks = 0; ks < 2; ++ks) {
                const int jl = ch * 64 + ks * 32 + quad * 8;
                float4 sa = *(const float4*)&s2s[jl];
                float4 sb = *(const float4*)&s2s[jl + 4];
                const float sv[8] = {sa.x, sa.y, sa.z, sa.w, sb.x, sb.y, sb.z, sb.w};
                union { u32 u[4]; short8 s; } cv;
#pragma unroll
                for (int jh = 0; jh < 4; ++jh) {
                    float w2[2];
#pragma unroll
                    for (int e = 0; e < 2; ++e) {
                        const int jj = jh * 2 + e;
                        const u32 word = m8[(jj & 3) * 2 + (chi >> 1)];
                        const int sh = (chi & 1) * 16 + ks * 8 + quad * 2 + (jj >> 2);
                        const u32 mbit = (word >> sh) & 1u;
                        float sc = s1v + sv[jj];
                        sc = fmaxf(sc, LRELU_A * sc);
                        float w = mbit ? __expf(sc - MSH) : 0.f;
                        Lacc += w;
                        w2[e] = w;
                    }
                    cv.u[jh] = (u32)f2bf_rtn(w2[0]) | ((u32)f2bf_rtn(w2[1]) << 16);
                }
                fa[ks] = cv.s;
            }
            // 16 MFMAs consume the in-flight fb loads
#pragma unroll
            for (int ct = 0; ct < 8; ++ct) {
                acc[ct] = __builtin_amdgcn_mfma_f32_16x16x32_bf16(fa[0], fb0[ct], acc[ct], 0, 0, 0);
                acc[ct] = __builtin_amdgcn_mfma_f32_16x16x32_bf16(fa[1], fb1[ct], acc[ct], 0, 0, 0);
            }
        }
    }

    // L row-sum across quads
    Lacc += __shfl_xor(Lacc, 16, 64);
    Lacc += __shfl_xor(Lacc, 32, 64);
    if (lane < 16)
        Lpart[(size_t)blockIdx.y * N_NODES + i_lane] = Lacc;

    // O partials (C layout: row = quad*4+reg, col = ct*16+n)
    const size_t obase = (size_t)blockIdx.y * N_NODES * OUT_F;
#pragma unroll
    for (int ct = 0; ct < 8; ++ct) {
#pragma unroll
        for (int r = 0; r < 4; ++r) {
            const int i = i0 + wid * 16 + quad * 4 + r;
            Opart[obase + (size_t)i * OUT_F + ct * 16 + n] = acc[ct][r];
        }
    }
}

// ---------------- combine partials, normalize, column stats via atomics ----------------
// grid 512 x 256 thr; block = 16 i-rows
__global__ __launch_bounds__(256) void k_comb(const float* __restrict__ Opart, const float* __restrict__ Lpart,
                                              float* __restrict__ hp, float* __restrict__ cs, float* __restrict__ cq) {
    const int t = threadIdx.x;
    const int c = t & 127, half = t >> 7;
    const int ibase = blockIdx.x * 16;
    float sv = 0.f, sq = 0.f;
    for (int k = 0; k < 8; k++) {
        const int i = ibase + half + (k << 1);
        float o = 0.f, L = 0.f;
#pragma unroll
        for (int s = 0; s < NSPLIT; s++) {
            o += Opart[((size_t)s * N_NODES + i) * OUT_F + c];
            L += Lpart[(size_t)s * N_NODES + i];
        }
        float v = L > 0.f ? o / L : 0.f;
        hp[(size_t)i * OUT_F + c] = v;
        sv += v; sq += v * v;
    }
    __shared__ float red[256];
    red[t] = sv; __syncthreads();
    if (half == 0) atomicAdd(&cs[c], sv + red[t + 128]);
    __syncthreads(); red[t] = sq; __syncthreads();
    if (half == 0) atomicAdd(&cq[c], sq + red[t + 128]);
}

// ---------------- batchnorm + elu + f32 out ----------------
__global__ __launch_bounds__(256) void k_bn(const float* __restrict__ hp, const float* __restrict__ cs,
                                            const float* __restrict__ cq, const float* __restrict__ gamma,
                                            const float* __restrict__ beta, float* __restrict__ out) {
    const int idx = blockIdx.x * 256 + threadIdx.x;   // 1M
    const int c = idx & 127;
    const float mean = cs[c] * (1.f / N_NODES);
    const float var  = cq[c] * (1.f / N_NODES) - mean * mean;
    float x = (hp[idx] - mean) * rsqrtf(var + EPS_BN) * gamma[c] + beta[c];
    x = x > 0.f ? x : expm1f(x);
    out[idx] = x;
}

extern "C" void kernel_launch(void* const* d_in, const int* in_sizes, int n_in,
                              void* d_out, int out_size, void* d_ws, size_t ws_size,
                              hipStream_t stream) {
    (void)in_sizes; (void)n_in; (void)out_size; (void)ws_size;
    const float* inp   = (const float*)d_in[0];
    const int*   adj   = (const int*)d_in[1];
    const float* W     = (const float*)d_in[2];
    const float* a     = (const float*)d_in[3];
    const float* gamma = (const float*)d_in[4];
    const float* beta  = (const float*)d_in[5];
    float* out = (float*)d_out;

    char* wsb = (char*)d_ws;
    u16*   hamT = (u16*)wsb;   wsb += (size_t)OUT_F * IN_F * 2;               // 128 KB
    u16*   hT   = (u16*)wsb;   wsb += (size_t)OUT_F * N_NODES * 2;            // 2 MB
    float* s1   = (float*)wsb; wsb += N_NODES * 4;
    float* s2   = (float*)wsb; wsb += N_NODES * 4;
    float* Op   = (float*)wsb; wsb += (size_t)NSPLIT * N_NODES * OUT_F * 4;   // 32 MB
    float* Lp   = (float*)wsb; wsb += (size_t)NSPLIT * N_NODES * 4;
    float* hp   = (float*)wsb; wsb += (size_t)N_NODES * OUT_F * 4;            // 4 MB
    float* cs   = (float*)wsb; wsb += OUT_F * 4;
    float* cq   = (float*)wsb; wsb += OUT_F * 4;

    hipLaunchKernelGGL(k_hamT, dim3(256), dim3(256), 0, stream, W, hamT, s1, s2, cs, cq);
    hipLaunchKernelGGL(k_h,    dim3(128, 2), dim3(256), 0, stream, inp, hamT, a, hT, s1, s2);
    hipLaunchKernelGGL(k_att,  dim3(128, NSPLIT), dim3(256), 0, stream, adj, hT, s1, s2, Op, Lp);
    hipLaunchKernelGGL(k_comb, dim3(512), dim3(256), 0, stream, Op, Lp, hp, cs, cq);
    hipLaunchKernelGGL(k_bn,   dim3(4096), dim3(256), 0, stream, hp, cs, cq, gamma, beta, out);
}

// Round 2
// 454.954 us; speedup vs baseline: 1.2509x; 1.2509x over previous
//
#include <hip/hip_runtime.h>
#include <hip/hip_bf16.h>
#include <math.h>

#define N_NODES 8192
#define IN_F    512
#define OUT_F   128
#define LRELU_A 0.2f
#define EPS_BN  1e-5f
#define MSH     40.0f                // static softmax shift (upper bound on lrelu(max s1+max s2))
#define NSPLIT  8
#define JSPAN   (N_NODES / NSPLIT)   // 1024
#define TILE_I  64                   // 4 waves x 16 rows

typedef unsigned short u16;
typedef unsigned int   u32;
typedef unsigned long long u64;
typedef __attribute__((ext_vector_type(8))) short  short8;
typedef __attribute__((ext_vector_type(4))) float  floatx4;

__device__ __forceinline__ u16 f2bf_rtn(float x) {
    u32 u = __float_as_uint(x);
    return (u16)((u + 0x7fffu + ((u >> 16) & 1u)) >> 16);
}

// ---------------- hamT bf16 [128 c][512 k]; zero s1/s2/cs/cq ----------------
__global__ __launch_bounds__(256) void k_hamT(const float* __restrict__ W, u16* __restrict__ hamT,
                                              float* __restrict__ s1, float* __restrict__ s2,
                                              float* __restrict__ cs, float* __restrict__ cq) {
    const int idx = blockIdx.x * 256 + threadIdx.x;   // 65536
    if (idx < N_NODES) { s1[idx] = 0.f; s2[idx] = 0.f; }
    if (idx < OUT_F)   { cs[idx] = 0.f; cq[idx] = 0.f; }
    const int c = idx >> 9, k = idx & 511;
    const int b = c >> 5, cc = c & 31, p = k >> 7, q = k & 127;
    const u32 NEGMASK = 0x284Eu;     // bit (b*4+p) set => sign -1
    const float sg = ((NEGMASK >> (b * 4 + p)) & 1u) ? -1.f : 1.f;
    hamT[idx] = f2bf_rtn(sg * W[q * 128 + (b ^ p) * 32 + cc]);
}

// ---------------- h = input @ ham via MFMA; K split across waves, 1 barrier total ----------------
// grid 512 x 256 thr. Block: 16 i-rows x 128 c; wave w owns K-slice [w*128, w*128+128).
// Cross-wave acc reduction in LDS -> hT store; s1/s2 partials via atomics (k-partial correct).
__global__ __launch_bounds__(256) void k_h(const float* __restrict__ inp, const u16* __restrict__ hamT,
                                           const float* __restrict__ a,
                                           u16* __restrict__ hT, float* __restrict__ s1, float* __restrict__ s2) {
    __shared__ float red[4][128][20];      // 40960 B; [wave][c][i_local(16)+pad4]
    const int t = threadIdx.x;
    const int lane = t & 63, wid = t >> 6;
    const int quad = lane >> 4, n = lane & 15;
    const int i0 = blockIdx.x * 16;
    const int kb = wid * 128;

    floatx4 acc[8];
#pragma unroll
    for (int ct = 0; ct < 8; ++ct) acc[ct] = (floatx4){0.f, 0.f, 0.f, 0.f};

#pragma unroll
    for (int ks = 0; ks < 4; ++ks) {
        const float* ap = inp + (size_t)(i0 + n) * IN_F + kb + ks * 32 + quad * 8;
        float4 a0 = *(const float4*)ap;
        float4 a1 = *(const float4*)(ap + 4);
        union { u32 u[4]; short8 s; } fa;
        fa.u[0] = (u32)f2bf_rtn(a0.x) | ((u32)f2bf_rtn(a0.y) << 16);
        fa.u[1] = (u32)f2bf_rtn(a0.z) | ((u32)f2bf_rtn(a0.w) << 16);
        fa.u[2] = (u32)f2bf_rtn(a1.x) | ((u32)f2bf_rtn(a1.y) << 16);
        fa.u[3] = (u32)f2bf_rtn(a1.z) | ((u32)f2bf_rtn(a1.w) << 16);
#pragma unroll
        for (int ct = 0; ct < 8; ++ct) {
            short8 fb = *(const short8*)&hamT[(ct * 16 + n) * IN_F + kb + ks * 32 + quad * 8];
            acc[ct] = __builtin_amdgcn_mfma_f32_16x16x32_bf16(fa.s, fb, acc[ct], 0, 0, 0);
        }
    }

    // s1/s2 partials (this wave's K-slice; full c) -> global atomics
    {
        float p1[4] = {0.f, 0.f, 0.f, 0.f}, p2[4] = {0.f, 0.f, 0.f, 0.f};
#pragma unroll
        for (int ct = 0; ct < 8; ++ct) {
            const int c = ct * 16 + n;
            const float a1v = a[c], a2v = a[OUT_F + c];
#pragma unroll
            for (int r = 0; r < 4; ++r) { p1[r] += acc[ct][r] * a1v; p2[r] += acc[ct][r] * a2v; }
        }
#pragma unroll
        for (int m = 1; m < 16; m <<= 1) {
#pragma unroll
            for (int r = 0; r < 4; ++r) {
                p1[r] += __shfl_xor(p1[r], m, 64);
                p2[r] += __shfl_xor(p2[r], m, 64);
            }
        }
        if (n == 0) {
#pragma unroll
            for (int r = 0; r < 4; ++r) {
                atomicAdd(&s1[i0 + quad * 4 + r], p1[r]);
                atomicAdd(&s2[i0 + quad * 4 + r], p2[r]);
            }
        }
    }

    // cross-wave reduce -> hT (bf16, [c][i] layout)
#pragma unroll
    for (int ct = 0; ct < 8; ++ct)
        *(float4*)&red[wid][ct * 16 + n][quad * 4] = *(float4*)&acc[ct];
    __syncthreads();

    {
        const int c = t >> 1, ih = (t & 1) * 8;
        float v[8];
#pragma unroll
        for (int e = 0; e < 8; ++e)
            v[e] = red[0][c][ih + e] + red[1][c][ih + e] + red[2][c][ih + e] + red[3][c][ih + e];
        uint4 pk;
        pk.x = (u32)f2bf_rtn(v[0]) | ((u32)f2bf_rtn(v[1]) << 16);
        pk.y = (u32)f2bf_rtn(v[2]) | ((u32)f2bf_rtn(v[3]) << 16);
        pk.z = (u32)f2bf_rtn(v[4]) | ((u32)f2bf_rtn(v[5]) << 16);
        pk.w = (u32)f2bf_rtn(v[6]) | ((u32)f2bf_rtn(v[7]) << 16);
        *(uint4*)&hT[(size_t)c * N_NODES + i0 + ih] = pk;
    }
}

// ---------------- fused MFMA attention: LDS-staged hT (dbuf, XOR-swizzled), masks in registers ----------------
// grid (128, NSPLIT) x 256 thr. Block: 64 i x 128 c over JSPAN=1024 j; 16 chunks of 64 j.
// Phase A: coalesced adj reads + ballot; lane n keeps the ballots of its own row (rr==n) in VGPRs.
// Phase B: fully unrolled 16 chunks (static mask reg indices); reg-prefetch of next hT chunk;
// s2 read direct from global (4 KB slice, L1-hot). LDS = 32 KB -> 4 blocks/CU.
__global__ __launch_bounds__(256, 4) void k_att(const int* __restrict__ adj, const u16* __restrict__ hT,
                                                const float* __restrict__ s1, const float* __restrict__ s2,
                                                float* __restrict__ Opart, float* __restrict__ Lpart) {
    __shared__ u16 hs[2][128 * 64];        // 2 x 16384 B, XOR-swizzled rows
    const int t = threadIdx.x;
    const int lane = t & 63, wid = t >> 6;
    const int quad = lane >> 4, n = lane & 15;
    const int i0 = blockIdx.x * TILE_I;
    const int jbase = blockIdx.y * JSPAN;
    const int i_lane = i0 + wid * 16 + n;
    const float s1v = s1[i_lane];
    const int scr = t >> 3, scj = (t & 7) * 8;      // hT staging: 32 c-rows/pass, 16 B/thread

    // ---- Phase A: ballot-pack adj rows; lane n keeps row (wid*16+n)'s masks in regs ----
    u32 M[4][8];
#pragma unroll
    for (int g = 0; g < 4; ++g)
#pragma unroll
        for (int w = 0; w < 8; ++w) M[g][w] = 0u;
    {
        const size_t rowbase = (size_t)(i0 + wid * 16);
#pragma unroll 4
        for (int rr = 0; rr < 16; ++rr) {
            const int* ap = adj + (rowbase + rr) * N_NODES + jbase + lane * 4;
            uint4 v[4];
#pragma unroll
            for (int g = 0; g < 4; ++g) v[g] = *(const uint4*)(ap + g * 256);
            const bool kp = (n == rr);
#pragma unroll
            for (int g = 0; g < 4; ++g) {
                u64 c0 = __ballot((int)v[g].x > 0);
                u64 c1 = __ballot((int)v[g].y > 0);
                u64 c2 = __ballot((int)v[g].z > 0);
                u64 c3 = __ballot((int)v[g].w > 0);
                if (kp) {
                    M[g][0] = (u32)c0; M[g][1] = (u32)(c0 >> 32);
                    M[g][2] = (u32)c1; M[g][3] = (u32)(c1 >> 32);
                    M[g][4] = (u32)c2; M[g][5] = (u32)(c2 >> 32);
                    M[g][6] = (u32)c3; M[g][7] = (u32)(c3 >> 32);
                }
            }
        }
    }

    // ---- stage hT chunk 0 (swizzled write) ----
#pragma unroll
    for (int ps = 0; ps < 4; ++ps) {
        const int cr = ps * 32 + scr;
        uint4 v = *(const uint4*)&hT[(size_t)cr * N_NODES + jbase + scj];
        *(uint4*)&hs[0][cr * 64 + (scj ^ ((cr & 7) * 8))] = v;
    }
    __syncthreads();

    floatx4 acc[8];
#pragma unroll
    for (int ct = 0; ct < 8; ct++) acc[ct] = (floatx4){0.f, 0.f, 0.f, 0.f};
    float Lacc = 0.f;

#pragma unroll
    for (int g = 0; g < 4; ++g) {
#pragma unroll
        for (int chi = 0; chi < 4; ++chi) {
            const int ch = g * 4 + chi;
            const int cur = ch & 1;
            const bool more = (ch + 1 < 16);
            // prefetch next chunk's hT (regs; LDS write after compute)
            uint4 H[4];
            if (more) {
#pragma unroll
                for (int ps = 0; ps < 4; ++ps) {
                    const int cr = ps * 32 + scr;
                    H[ps] = *(const uint4*)&hT[(size_t)cr * N_NODES + jbase + (ch + 1) * 64 + scj];
                }
            }
            // build A-frags (attention weights) for this chunk's 64 j; s2 direct from global (L1)
            short8 fa[2];
#pragma unroll
            for (int ks = 0; ks < 2; ++ks) {
                const float* s2p = s2 + jbase + ch * 64 + ks * 32 + quad * 8;
                float4 sa = *(const float4*)s2p;
                float4 sb = *(const float4*)(s2p + 4);
                const float sv[8] = {sa.x, sa.y, sa.z, sa.w, sb.x, sb.y, sb.z, sb.w};
                union { u32 u[4]; short8 s; } cv;
#pragma unroll
                for (int jh = 0; jh < 4; ++jh) {
                    float w2[2];
#pragma unroll
                    for (int e = 0; e < 2; ++e) {
                        const int jj = jh * 2 + e;
                        const u32 word = M[g][(jj & 3) * 2 + (chi >> 1)];   // all-static reg index
                        const int sh = (chi & 1) * 16 + ks * 8 + quad * 2 + (jj >> 2);
                        const u32 mbit = (word >> sh) & 1u;
                        float sc = s1v + sv[jj];
                        sc = fmaxf(sc, LRELU_A * sc);
                        float w = mbit ? __expf(sc - MSH) : 0.f;
                        Lacc += w;
                        w2[e] = w;
                    }
                    cv.u[jh] = (u32)f2bf_rtn(w2[0]) | ((u32)f2bf_rtn(w2[1]) << 16);
                }
                fa[ks] = cv.s;
            }
            // 16 MFMAs from LDS (swizzled reads: conflict-free)
#pragma unroll
            for (int ct = 0; ct < 8; ++ct) {
                const int rb = ct * 16 + n;
                const int sw = (rb & 7) * 8;
                short8 fb0 = *(const short8*)&hs[cur][rb * 64 + ((quad * 8) ^ sw)];
                short8 fb1 = *(const short8*)&hs[cur][rb * 64 + ((32 + quad * 8) ^ sw)];
                acc[ct] = __builtin_amdgcn_mfma_f32_16x16x32_bf16(fa[0], fb0, acc[ct], 0, 0, 0);
                acc[ct] = __builtin_amdgcn_mfma_f32_16x16x32_bf16(fa[1], fb1, acc[ct], 0, 0, 0);
            }
            // write prefetched chunk to alternate buffer (swizzled)
            if (more) {
#pragma unroll
                for (int ps = 0; ps < 4; ++ps) {
                    const int cr = ps * 32 + scr;
                    *(uint4*)&hs[cur ^ 1][cr * 64 + (scj ^ ((cr & 7) * 8))] = H[ps];
                }
            }
            __syncthreads();
        }
    }

    // L row-sum across quads
    Lacc += __shfl_xor(Lacc, 16, 64);
    Lacc += __shfl_xor(Lacc, 32, 64);
    if (lane < 16)
        Lpart[(size_t)blockIdx.y * N_NODES + i_lane] = Lacc;

    // O partials (C layout: row = quad*4+reg, col = ct*16+n)
    const size_t obase = (size_t)blockIdx.y * N_NODES * OUT_F;
#pragma unroll
    for (int ct = 0; ct < 8; ++ct) {
#pragma unroll
        for (int r = 0; r < 4; ++r) {
            const int i = i0 + wid * 16 + quad * 4 + r;
            Opart[obase + (size_t)i * OUT_F + ct * 16 + n] = acc[ct][r];
        }
    }
}

// ---------------- combine partials, normalize, column stats via atomics ----------------
// grid 512 x 256 thr; block = 16 i-rows
__global__ __launch_bounds__(256) void k_comb(const float* __restrict__ Opart, const float* __restrict__ Lpart,
                                              float* __restrict__ hp, float* __restrict__ cs, float* __restrict__ cq) {
    const int t = threadIdx.x;
    const int c = t & 127, half = t >> 7;
    const int ibase = blockIdx.x * 16;
    float sv = 0.f, sq = 0.f;
    for (int k = 0; k < 8; k++) {
        const int i = ibase + half + (k << 1);
        float o = 0.f, L = 0.f;
#pragma unroll
        for (int s = 0; s < NSPLIT; s++) {
            o += Opart[((size_t)s * N_NODES + i) * OUT_F + c];
            L += Lpart[(size_t)s * N_NODES + i];
        }
        float v = L > 0.f ? o / L : 0.f;
        hp[(size_t)i * OUT_F + c] = v;
        sv += v; sq += v * v;
    }
    __shared__ float red[256];
    red[t] = sv; __syncthreads();
    if (half == 0) atomicAdd(&cs[c], sv + red[t + 128]);
    __syncthreads(); red[t] = sq; __syncthreads();
    if (half == 0) atomicAdd(&cq[c], sq + red[t + 128]);
}

// ---------------- batchnorm + elu + f32 out ----------------
__global__ __launch_bounds__(256) void k_bn(const float* __restrict__ hp, const float* __restrict__ cs,
                                            const float* __restrict__ cq, const float* __restrict__ gamma,
                                            const float* __restrict__ beta, float* __restrict__ out) {
    const int idx = blockIdx.x * 256 + threadIdx.x;   // 1M
    const int c = idx & 127;
    const float mean = cs[c] * (1.f / N_NODES);
    const float var  = cq[c] * (1.f / N_NODES) - mean * mean;
    float x = (hp[idx] - mean) * rsqrtf(var + EPS_BN) * gamma[c] + beta[c];
    x = x > 0.f ? x : expm1f(x);
    out[idx] = x;
}

extern "C" void kernel_launch(void* const* d_in, const int* in_sizes, int n_in,
                              void* d_out, int out_size, void* d_ws, size_t ws_size,
                              hipStream_t stream) {
    (void)in_sizes; (void)n_in; (void)out_size; (void)ws_size;
    const float* inp   = (const float*)d_in[0];
    const int*   adj   = (const int*)d_in[1];
    const float* W     = (const float*)d_in[2];
    const float* a     = (const float*)d_in[3];
    const float* gamma = (const float*)d_in[4];
    const float* beta  = (const float*)d_in[5];
    float* out = (float*)d_out;

    char* wsb = (char*)d_ws;
    u16*   hamT = (u16*)wsb;   wsb += (size_t)OUT_F * IN_F * 2;               // 128 KB
    u16*   hT   = (u16*)wsb;   wsb += (size_t)OUT_F * N_NODES * 2;            // 2 MB
    float* s1   = (float*)wsb; wsb += N_NODES * 4;
    float* s2   = (float*)wsb; wsb += N_NODES * 4;
    float* Op   = (float*)wsb; wsb += (size_t)NSPLIT * N_NODES * OUT_F * 4;   // 32 MB
    float* Lp   = (float*)wsb; wsb += (size_t)NSPLIT * N_NODES * 4;
    float* hp   = (float*)wsb; wsb += (size_t)N_NODES * OUT_F * 4;            // 4 MB
    float* cs   = (float*)wsb; wsb += OUT_F * 4;
    float* cq   = (float*)wsb; wsb += OUT_F * 4;

    hipLaunchKernelGGL(k_hamT, dim3(256), dim3(256), 0, stream, W, hamT, s1, s2, cs, cq);
    hipLaunchKernelGGL(k_h,    dim3(512), dim3(256), 0, stream, inp, hamT, a, hT, s1, s2);
    hipLaunchKernelGGL(k_att,  dim3(128, NSPLIT), dim3(256), 0, stream, adj, hT, s1, s2, Op, Lp);
    hipLaunchKernelGGL(k_comb, dim3(512), dim3(256), 0, stream, Op, Lp, hp, cs, cq);
    hipLaunchKernelGGL(k_bn,   dim3(4096), dim3(256), 0, stream, hp, cs, cq, gamma, beta, out);
}